// Round 4
// baseline (336.302 us; speedup 1.0000x reference)
//
#include <hip/hip_runtime.h>
#include <hip/hip_bf16.h>

typedef __hip_bfloat16 bf16;
typedef __bf16 bfx8 __attribute__((ext_vector_type(8)));
typedef float f32x4 __attribute__((ext_vector_type(4)));

#define BM 128
#define BN 128
#define BK 32

typedef __attribute__((address_space(3))) void lds_void_t;
typedef const __attribute__((address_space(1))) void gbl_void_t;

// HW fp32 atomic add (global_atomic_add_f32); d_out is coarse-grained hipMalloc
__device__ __forceinline__ void atomAddF(float* p, float v) { unsafeAtomicAdd(p, v); }

// ---------------------------------------------------------------------------
// Fused prep: HT[e][n] = bf16(H[n][e]); de[e] += colsum; dvr[n] += row·w
// H binary -> bf16 exact. grid (E/64, N/64), block 256.
__global__ void prep_kernel(const float* __restrict__ H, const float* __restrict__ w,
                            bf16* __restrict__ HT, float* __restrict__ de,
                            float* __restrict__ dvr, int N, int E) {
    __shared__ bf16 tile[64][65];
    __shared__ float cred[4][64];
    __shared__ float rred[4][64];
    int eb = blockIdx.x * 64, nb = blockIdx.y * 64;
    int tid = threadIdx.x;
    int c = tid & 63, g = tid >> 6;

    float cs = 0.f;
#pragma unroll
    for (int k = 0; k < 16; k++) {
        int r = g + (k << 2);
        float v = H[(size_t)(nb + r) * E + eb + c];
        tile[r][c] = __float2bfloat16(v);
        cs += v;
    }
    cred[g][c] = cs;
    __syncthreads();
    if (g == 0) {
        float s = cred[0][c] + cred[1][c] + cred[2][c] + cred[3][c];
        atomicAdd(&de[eb + c], s);
    }
    float rs = 0.f;
#pragma unroll
    for (int k = 0; k < 16; k++) {
        int cc = g + (k << 2);
        rs += __bfloat162float(tile[c][cc]) * w[eb + cc];
    }
    rred[g][c] = rs;
    __syncthreads();
    if (g == 1) {
        float s = rred[0][c] + rred[1][c] + rred[2][c] + rred[3][c];
        atomicAdd(&dvr[nb + c], s);
    }
#pragma unroll
    for (int k = 0; k < 16; k++) {
        int r = g + (k << 2);
        HT[(size_t)(eb + r) * N + nb + c] = tile[c][r];
    }
}

__global__ void finalize_kernel(const float* __restrict__ dvr, const float* __restrict__ de,
                                const float* __restrict__ w, float* __restrict__ dv_is,
                                float* __restrict__ wsc, int N, int E) {
    int i = blockIdx.x * 256 + threadIdx.x;
    if (i < N) dv_is[i] = rsqrtf(dvr[i] + 1e-8f);
    if (i < E) wsc[i] = w[i] / (de[i] + 1e-8f);
}

// generic f32 -> bf16, 8 elems/thread
__global__ void f2b_kernel(const float* __restrict__ src, bf16* __restrict__ dst) {
    size_t i = ((size_t)blockIdx.x * 256 + threadIdx.x) * 8;
    f32x4 p0 = *(const f32x4*)&src[i];
    f32x4 p1 = *(const f32x4*)&src[i + 4];
    bfx8 v;
#pragma unroll
    for (int t = 0; t < 4; t++) { v[t] = (__bf16)p0[t]; v[4 + t] = (__bf16)p1[t]; }
    *(bfx8*)&dst[i] = v;
}

// Hb[n][e] = bf16(dv_is[n] * H[n][e])  (H binary: one rounding of dv_is per row)
__global__ void hb_kernel(const float* __restrict__ H, const float* __restrict__ dv_is,
                          bf16* __restrict__ Hb) {
    size_t i = ((size_t)blockIdx.x * 256 + threadIdx.x) * 8;
    float s = dv_is[i >> 11];  // E = 2048, chunk stays in one row
    f32x4 p0 = *(const f32x4*)&H[i];
    f32x4 p1 = *(const f32x4*)&H[i + 4];
    bfx8 v;
#pragma unroll
    for (int t = 0; t < 4; t++) { v[t] = (__bf16)(p0[t] * s); v[4 + t] = (__bf16)(p1[t] * s); }
    *(bfx8*)&Hb[i] = v;
}

// t_t[c][e] = bf16(tf[c][e] * wsc[e])
__global__ void tconv_kernel(const float* __restrict__ tf, const float* __restrict__ wsc,
                             bf16* __restrict__ tt) {
    size_t i = ((size_t)blockIdx.x * 256 + threadIdx.x) * 8;
    size_t e = i & 2047;
    f32x4 p0 = *(const f32x4*)&tf[i];
    f32x4 p1 = *(const f32x4*)&tf[i + 4];
    f32x4 w0 = *(const f32x4*)&wsc[e];
    f32x4 w1 = *(const f32x4*)&wsc[e + 4];
    bfx8 v;
#pragma unroll
    for (int t = 0; t < 4; t++) { v[t] = (__bf16)(p0[t] * w0[t]); v[4 + t] = (__bf16)(p1[t] * w1[t]); }
    *(bfx8*)&tt[i] = v;
}

// ---------------------------------------------------------------------------
// Async B^T-form GEMM (m97 structure), bf16 operands, global_load_lds w=16,
// unpadded stride-32 LDS. C[row][col] = sum_k A[row][k]*Bt[col][k]
// MODE 0: z = batch b: B += z*1048576; C row += z*256;
//         store bf16 (acc + rvec[row])*cvec[col] at C[row*ldc+col]  (K3)
// MODE 1: z = k-slice: kBase = z*kLen; atomicAdd f32 C[row*ldc+col] (K4)
// MODE 2: z = k-slice: atomicAdd f32 C[(col>>8)*1048576+row*256+(col&255)] (K5)
template <int MODE>
__global__ __launch_bounds__(256) void gemm_bt_async(
    const bf16* __restrict__ A, const bf16* __restrict__ Bt, int K, int kLen,
    void* __restrict__ Cv, int ldc,
    const float* __restrict__ rvec, const float* __restrict__ cvec) {
    __shared__ __align__(16) bf16 As[BM * 32];
    __shared__ __align__(16) bf16 Bs[BN * 32];

    const int tid     = threadIdx.x;
    const int rowBase = blockIdx.y * BM;
    const int colBase = blockIdx.x * BN;
    const int wave = tid >> 6, lane = tid & 63;
    const int wr = (wave >> 1) * 64;
    const int wc = (wave & 1) * 64;
    const int lcol = lane & 15, quad = lane >> 4;

    const bf16* Ap = A;
    const bf16* Bp = Bt;
    int kBase = 0;
    size_t cRowOff = 0;
    if (MODE == 0) {
        Bp += (size_t)blockIdx.z * 1048576;   // x batch stride (4096*256)
        cRowOff = (size_t)blockIdx.z * 256;
    } else {
        kBase = blockIdx.z * kLen;
    }

    // staging map: LDS byte = tid*16 (wave-uniform base + lane*16)
    const int sr = tid >> 2, skc = (tid & 3) << 3;
    const bf16* a0 = &Ap[(size_t)(rowBase + sr) * K + skc];
    const bf16* a1 = a0 + (size_t)64 * K;
    const bf16* b0 = &Bp[(size_t)(colBase + sr) * K + skc];
    const bf16* b1 = b0 + (size_t)64 * K;
    bf16* asd0 = &As[sr * 32 + skc];
    bf16* asd1 = &As[(sr + 64) * 32 + skc];
    bf16* bsd0 = &Bs[sr * 32 + skc];
    bf16* bsd1 = &Bs[(sr + 64) * 32 + skc];

    f32x4 acc[4][4];
#pragma unroll
    for (int i = 0; i < 4; i++)
#pragma unroll
        for (int j = 0; j < 4; j++) acc[i][j] = (f32x4){0.f, 0.f, 0.f, 0.f};

    for (int k0 = kBase; k0 < kBase + kLen; k0 += BK) {
        __builtin_amdgcn_global_load_lds((gbl_void_t*)(a0 + k0), (lds_void_t*)asd0, 16, 0, 0);
        __builtin_amdgcn_global_load_lds((gbl_void_t*)(a1 + k0), (lds_void_t*)asd1, 16, 0, 0);
        __builtin_amdgcn_global_load_lds((gbl_void_t*)(b0 + k0), (lds_void_t*)bsd0, 16, 0, 0);
        __builtin_amdgcn_global_load_lds((gbl_void_t*)(b1 + k0), (lds_void_t*)bsd1, 16, 0, 0);
        __syncthreads();

        bfx8 af[4], bfr[4];
#pragma unroll
        for (int i = 0; i < 4; i++)
            af[i] = *(const bfx8*)&As[(wr + i * 16 + lcol) * 32 + quad * 8];
#pragma unroll
        for (int j = 0; j < 4; j++)
            bfr[j] = *(const bfx8*)&Bs[(wc + j * 16 + lcol) * 32 + quad * 8];
#pragma unroll
        for (int i = 0; i < 4; i++)
#pragma unroll
            for (int j = 0; j < 4; j++)
                acc[i][j] = __builtin_amdgcn_mfma_f32_16x16x32_bf16(af[i], bfr[j], acc[i][j], 0, 0, 0);
        __syncthreads();
    }

    // C/D layout: col = lane&15, row = quad*4 + reg  [verified m89/m91]
    bf16*  Cb = (bf16*)Cv;
    float* Cf = (float*)Cv;
#pragma unroll
    for (int i = 0; i < 4; i++) {
#pragma unroll
        for (int j = 0; j < 4; j++) {
#pragma unroll
            for (int r = 0; r < 4; r++) {
                int grow = rowBase + wr + i * 16 + quad * 4 + r;
                int gcol = colBase + wc + j * 16 + lcol;
                float v = acc[i][j][r];
                if (MODE == 0) {
                    v = (v + rvec[grow]) * cvec[gcol];
                    Cb[(cRowOff + grow) * (size_t)ldc + gcol] = __float2bfloat16(v);
                } else if (MODE == 1) {
                    atomAddF(&Cf[(size_t)grow * ldc + gcol], v);
                } else {
                    atomAddF(&Cf[(size_t)(gcol >> 8) * 1048576 + (size_t)grow * 256 + (gcol & 255)], v);
                }
            }
        }
    }
}

// ---------------------------------------------------------------------------
extern "C" void kernel_launch(void* const* d_in, const int* in_sizes, int n_in,
                              void* d_out, int out_size, void* d_ws, size_t ws_size,
                              hipStream_t stream) {
    const float* x    = (const float*)d_in[0];  // [8,4096,256]
    const float* ew   = (const float*)d_in[1];  // [2048]
    const float* H    = (const float*)d_in[2];  // [4096,2048]
    const float* W    = (const float*)d_in[3];  // [256,256]
    const float* bias = (const float*)d_in[4];  // [256]
    float* out = (float*)d_out;                 // [8,4096,256] f32, 33.5 MB

    const int N = 4096, E = 2048;

    // ws layout (proven 40.06 MB footprint)
    char* ws = (char*)d_ws;
    float* de    = (float*)(ws);               // 2048 f32
    float* dvr   = (float*)(ws + 8192);        // 4096 f32
    float* dv_is = (float*)(ws + 24576);       // 4096 f32
    float* wsc   = (float*)(ws + 40960);       // 2048 f32
    bf16*  HT    = (bf16*)(ws + 65536);                // [E][N] 16 MB; later Hb [N][E]
    bf16*  xs_t  = (bf16*)(ws + 65536 + 16777216);     // [2048][4096] 16 MB
    bf16*  t_t   = (bf16*)(ws + 65536 + 2 * 16777216); // [2048][2048]  8 MB

    // d_out scratch phases: [0:16MB) = xb (K3 input), then t_t_f32 (K4 target);
    // [16MB:16.125MB) = Wb. Fully re-zeroed before K5.
    bf16*  xb    = (bf16*)d_out;               // [8*4096,256] bf16, 16 MB
    bf16*  Wb    = (bf16*)d_out + 8388608;     // [256,256] bf16, 128 KB
    float* ttf   = (float*)d_out;              // [2048][2048] f32, 16 MB

    hipMemsetAsync(ws, 0, 24576, stream);  // de + dvr

    prep_kernel<<<dim3(E / 64, N / 64), 256, 0, stream>>>(H, ew, HT, de, dvr, N, E);
    finalize_kernel<<<dim3(16), 256, 0, stream>>>(dvr, de, ew, dv_is, wsc, N, E);

    // bf16 copies of W and x into d_out scratch
    f2b_kernel<<<dim3(65536 / 2048), 256, 0, stream>>>(W, Wb);
    f2b_kernel<<<dim3(8388608 / 2048), 256, 0, stream>>>(x, xb);

    // K3: xs_t[b*256+o][n] = (sum_d Wb[o][d]*xb[b*4096+n][d] + bias[o]) * dv_is[n]
    gemm_bt_async<0><<<dim3(4096 / BN, 256 / BM, 8), 256, 0, stream>>>(
        Wb, xb, 256, 256, xs_t, 4096, bias, dv_is);

    // K4 split-K=4: ttf[c][e] += sum_n xs_t[c][n]*HT[e][n]
    hipMemsetAsync(ttf, 0, 16777216, stream);
    gemm_bt_async<1><<<dim3(2048 / BN, 2048 / BM, 4), 256, 0, stream>>>(
        xs_t, HT, 4096, 1024, ttf, 2048, nullptr, nullptr);

    // t_t = bf16(ttf * wsc[e])
    tconv_kernel<<<dim3(4194304 / 2048), 256, 0, stream>>>(ttf, wsc, t_t);

    // Hb = bf16(dv_is[n] * H[n][e])   (overwrites HT, dead after K4)
    bf16* Hb = HT;
    hb_kernel<<<dim3(8388608 / 2048), 256, 0, stream>>>(H, dv_is, Hb);

    // K5 split-K=2: out[b][n][o] += sum_e Hb[n][e]*t_t[b*256+o][e]
    hipMemsetAsync(out, 0, (size_t)out_size * sizeof(float), stream);
    gemm_bt_async<2><<<dim3(2048 / BN, 4096 / BM, 2), 256, 0, stream>>>(
        Hb, t_t, 2048, 1024, out, 0, nullptr, nullptr);
}

// Round 5
// 255.254 us; speedup vs baseline: 1.3175x; 1.3175x over previous
//
#include <hip/hip_runtime.h>
#include <hip/hip_bf16.h>

typedef __hip_bfloat16 bf16;
typedef __bf16 bfx8 __attribute__((ext_vector_type(8)));
typedef float f32x4 __attribute__((ext_vector_type(4)));

#define BM 128
#define BN 128

typedef __attribute__((address_space(3))) void lds_void_t;
typedef const __attribute__((address_space(1))) void gbl_void_t;

// ---------------------------------------------------------------------------
// Fused prep: HT[e][n] = bf16(H[n][e]); Hb[n][e] = bf16(H[n][e]);
// de[e] += colsum; dvr[n] += row·w.  H binary -> bf16 exact.
// grid (E/64, N/64), block 256.
__global__ void prep_kernel(const float* __restrict__ H, const float* __restrict__ w,
                            bf16* __restrict__ HT, bf16* __restrict__ Hb,
                            float* __restrict__ de, float* __restrict__ dvr, int N, int E) {
    __shared__ bf16 tile[64][65];
    __shared__ float cred[4][64];
    __shared__ float rred[4][64];
    int eb = blockIdx.x * 64, nb = blockIdx.y * 64;
    int tid = threadIdx.x;
    int c = tid & 63, g = tid >> 6;

    float cs = 0.f;
#pragma unroll
    for (int k = 0; k < 16; k++) {
        int r = g + (k << 2);
        float v = H[(size_t)(nb + r) * E + eb + c];
        bf16 bv = __float2bfloat16(v);
        tile[r][c] = bv;
        Hb[(size_t)(nb + r) * E + eb + c] = bv;   // row-major bf16 copy (coalesced in e)
        cs += v;
    }
    cred[g][c] = cs;
    __syncthreads();
    if (g == 0) {
        float s = cred[0][c] + cred[1][c] + cred[2][c] + cred[3][c];
        atomicAdd(&de[eb + c], s);
    }
    float rs = 0.f;
#pragma unroll
    for (int k = 0; k < 16; k++) {
        int cc = g + (k << 2);
        rs += __bfloat162float(tile[c][cc]) * w[eb + cc];
    }
    rred[g][c] = rs;
    __syncthreads();
    if (g == 1) {
        float s = rred[0][c] + rred[1][c] + rred[2][c] + rred[3][c];
        atomicAdd(&dvr[nb + c], s);
    }
#pragma unroll
    for (int k = 0; k < 16; k++) {
        int r = g + (k << 2);
        HT[(size_t)(eb + r) * N + nb + c] = tile[c][r];  // transposed (coalesced in n)
    }
}

__global__ void finalize_kernel(const float* __restrict__ dvr, const float* __restrict__ de,
                                const float* __restrict__ w, float* __restrict__ dv_is,
                                float* __restrict__ wsc, int N, int E) {
    int i = blockIdx.x * 256 + threadIdx.x;
    if (i < N) dv_is[i] = rsqrtf(dvr[i] + 1e-8f);
    if (i < E) wsc[i] = w[i] / (de[i] + 1e-8f);
}

// ---------------------------------------------------------------------------
// Async B^T-form GEMM, BK=64 as two independent stride-32 LDS sub-buffers
// (same bank-proven layout as m97; one vmcnt drain per 2 k-chunks).
// XCD swizzle: lin&7 = XCD, each XCD covers a PX x PY block region.
// C[row][col] = sum_k A[row][k]*Bt[col][k]
// MODE 1: Cb[row*ldc+col] = bf16(acc * cvec[col])                      (K4)
// MODE 2: Cf[(col>>8)*1048576 + row*256 + (col&255)] = acc*rvec[row]   (K5)
template <int MODE, int PX, int PY>
__global__ __launch_bounds__(256) void gemm_bt_async(
    const bf16* __restrict__ A, const bf16* __restrict__ Bt, int K,
    void* __restrict__ Cv, int ldc,
    const float* __restrict__ rvec, const float* __restrict__ cvec) {
    __shared__ __align__(16) bf16 S[4][BM * 32];   // A0,A1,B0,B1 = 32 KB

    // XCD-aware block swizzle: consecutive lin round-robin XCDs; give each XCD
    // a compact PX x PY region so its L2 holds the region's A/B panels.
    const int lin = blockIdx.y * gridDim.x + blockIdx.x;
    const int xcd = lin & 7, sidx = lin >> 3;
    const int nx = gridDim.x / PX;
    const int bx = (xcd % nx) * PX + (sidx % PX);
    const int by = (xcd / nx) * PY + (sidx / PX);

    const int tid     = threadIdx.x;
    const int rowBase = by * BM;
    const int colBase = bx * BN;
    const int wave = tid >> 6, lane = tid & 63;
    const int wr = (wave >> 1) * 64;
    const int wc = (wave & 1) * 64;
    const int lcol = lane & 15, quad = lane >> 4;

    // staging map: LDS byte = tid*16 within each sub-buffer (wave-uniform + lane*16)
    const int sr = tid >> 2, skc = (tid & 3) << 3;
    const bf16* a0 = &A[(size_t)(rowBase + sr) * K + skc];
    const bf16* a1 = a0 + (size_t)64 * K;
    const bf16* b0 = &Bt[(size_t)(colBase + sr) * K + skc];
    const bf16* b1 = b0 + (size_t)64 * K;
    bf16* d_a0[2] = {&S[0][sr * 32 + skc], &S[1][sr * 32 + skc]};
    bf16* d_a1[2] = {&S[0][(sr + 64) * 32 + skc], &S[1][(sr + 64) * 32 + skc]};
    bf16* d_b0[2] = {&S[2][sr * 32 + skc], &S[3][sr * 32 + skc]};
    bf16* d_b1[2] = {&S[2][(sr + 64) * 32 + skc], &S[3][(sr + 64) * 32 + skc]};

    f32x4 acc[4][4];
#pragma unroll
    for (int i = 0; i < 4; i++)
#pragma unroll
        for (int j = 0; j < 4; j++) acc[i][j] = (f32x4){0.f, 0.f, 0.f, 0.f};

    for (int k0 = 0; k0 < K; k0 += 64) {
#pragma unroll
        for (int h = 0; h < 2; h++) {
            int kk = k0 + h * 32;
            __builtin_amdgcn_global_load_lds((gbl_void_t*)(a0 + kk), (lds_void_t*)d_a0[h], 16, 0, 0);
            __builtin_amdgcn_global_load_lds((gbl_void_t*)(a1 + kk), (lds_void_t*)d_a1[h], 16, 0, 0);
            __builtin_amdgcn_global_load_lds((gbl_void_t*)(b0 + kk), (lds_void_t*)d_b0[h], 16, 0, 0);
            __builtin_amdgcn_global_load_lds((gbl_void_t*)(b1 + kk), (lds_void_t*)d_b1[h], 16, 0, 0);
        }
        __syncthreads();

#pragma unroll
        for (int h = 0; h < 2; h++) {
            bfx8 af[4], bfr[4];
#pragma unroll
            for (int i = 0; i < 4; i++)
                af[i] = *(const bfx8*)&S[h][(wr + i * 16 + lcol) * 32 + quad * 8];
#pragma unroll
            for (int j = 0; j < 4; j++)
                bfr[j] = *(const bfx8*)&S[2 + h][(wc + j * 16 + lcol) * 32 + quad * 8];
#pragma unroll
            for (int i = 0; i < 4; i++)
#pragma unroll
                for (int j = 0; j < 4; j++)
                    acc[i][j] = __builtin_amdgcn_mfma_f32_16x16x32_bf16(af[i], bfr[j], acc[i][j], 0, 0, 0);
        }
        __syncthreads();
    }

    // C/D layout: col = lane&15, row = quad*4 + reg  [verified m89/m91]
    bf16*  Cb = (bf16*)Cv;
    float* Cf = (float*)Cv;
#pragma unroll
    for (int i = 0; i < 4; i++) {
#pragma unroll
        for (int j = 0; j < 4; j++) {
#pragma unroll
            for (int r = 0; r < 4; r++) {
                int grow = rowBase + wr + i * 16 + quad * 4 + r;
                int gcol = colBase + wc + j * 16 + lcol;
                float v = acc[i][j][r];
                if (MODE == 1) {
                    Cb[(size_t)grow * ldc + gcol] = __float2bfloat16(v * cvec[gcol]);
                } else {
                    Cf[(size_t)(gcol >> 8) * 1048576 + (size_t)grow * 256 + (gcol & 255)] =
                        v * rvec[grow];
                }
            }
        }
    }
}

// ---------------------------------------------------------------------------
// Sync-staged conv GEMM (K3): both operands f32, convert while staging.
// xs_t[bf16] = (acc + rvec[row]) * cvec[col]
__global__ __launch_bounds__(256) void gemm_bt_conv(
    const float* __restrict__ A, const float* __restrict__ B, int K,
    bf16* __restrict__ C, int ldc,
    const float* __restrict__ rvec, const float* __restrict__ cvec,
    long long bStride, long long cStride) {
    __shared__ __align__(16) bf16 As[BM * 40];
    __shared__ __align__(16) bf16 Bs[BN * 40];

    const float* Bp = B + (size_t)blockIdx.z * (size_t)bStride;
    bf16*        Cp = C + (size_t)blockIdx.z * (size_t)cStride;

    const int tid     = threadIdx.x;
    const int rowBase = blockIdx.y * BM;
    const int colBase = blockIdx.x * BN;
    const int wave = tid >> 6, lane = tid & 63;
    const int wr = (wave >> 1) * 64;
    const int wc = (wave & 1) * 64;
    const int lcol = lane & 15, quad = lane >> 4;

    f32x4 acc[4][4];
#pragma unroll
    for (int i = 0; i < 4; i++)
#pragma unroll
        for (int j = 0; j < 4; j++) acc[i][j] = (f32x4){0.f, 0.f, 0.f, 0.f};

    for (int k0 = 0; k0 < K; k0 += 32) {
#pragma unroll
        for (int c = 0; c < 2; c++) {
            int ch = tid + c * 256;
            int r = ch >> 2, kc = (ch & 3) << 3;
            size_t aoff = (size_t)(rowBase + r) * K + k0 + kc;
            size_t boff = (size_t)(colBase + r) * K + k0 + kc;
            f32x4 p0 = *(const f32x4*)&A[aoff];
            f32x4 p1 = *(const f32x4*)&A[aoff + 4];
            bfx8 va;
#pragma unroll
            for (int t = 0; t < 4; t++) { va[t] = (__bf16)p0[t]; va[4 + t] = (__bf16)p1[t]; }
            *(bfx8*)&As[r * 40 + kc] = va;
            f32x4 q0 = *(const f32x4*)&Bp[boff];
            f32x4 q1 = *(const f32x4*)&Bp[boff + 4];
            bfx8 vb;
#pragma unroll
            for (int t = 0; t < 4; t++) { vb[t] = (__bf16)q0[t]; vb[4 + t] = (__bf16)q1[t]; }
            *(bfx8*)&Bs[r * 40 + kc] = vb;
        }
        __syncthreads();

        bfx8 af[4], bfr[4];
#pragma unroll
        for (int i = 0; i < 4; i++)
            af[i] = *(const bfx8*)&As[(wr + i * 16 + lcol) * 40 + quad * 8];
#pragma unroll
        for (int j = 0; j < 4; j++)
            bfr[j] = *(const bfx8*)&Bs[(wc + j * 16 + lcol) * 40 + quad * 8];
#pragma unroll
        for (int i = 0; i < 4; i++)
#pragma unroll
            for (int j = 0; j < 4; j++)
                acc[i][j] = __builtin_amdgcn_mfma_f32_16x16x32_bf16(af[i], bfr[j], acc[i][j], 0, 0, 0);
        __syncthreads();
    }

#pragma unroll
    for (int i = 0; i < 4; i++) {
#pragma unroll
        for (int j = 0; j < 4; j++) {
#pragma unroll
            for (int r = 0; r < 4; r++) {
                int grow = rowBase + wr + i * 16 + quad * 4 + r;
                int gcol = colBase + wc + j * 16 + lcol;
                float v = (acc[i][j][r] + rvec[grow]) * cvec[gcol];
                Cp[(size_t)grow * ldc + gcol] = __float2bfloat16(v);
            }
        }
    }
}

// ---------------------------------------------------------------------------
extern "C" void kernel_launch(void* const* d_in, const int* in_sizes, int n_in,
                              void* d_out, int out_size, void* d_ws, size_t ws_size,
                              hipStream_t stream) {
    const float* x    = (const float*)d_in[0];  // [8,4096,256]
    const float* ew   = (const float*)d_in[1];  // [2048]
    const float* H    = (const float*)d_in[2];  // [4096,2048]
    const float* W    = (const float*)d_in[3];  // [256,256]
    const float* bias = (const float*)d_in[4];  // [256]
    float* out = (float*)d_out;                 // [8,4096,256] f32

    const int N = 4096, E = 2048;

    char* ws = (char*)d_ws;
    float* de    = (float*)(ws);               // 2048 f32
    float* dvr   = (float*)(ws + 8192);        // 4096 f32
    float* dv_is = (float*)(ws + 24576);       // 4096 f32
    float* wsc   = (float*)(ws + 40960);       // 2048 f32
    bf16*  HT    = (bf16*)(ws + 65536);                // [E][N] 16 MB
    bf16*  xs_t  = (bf16*)(ws + 65536 + 16777216);     // [2048][4096] 16 MB
    bf16*  t_t   = (bf16*)(ws + 65536 + 2 * 16777216); // [2048][2048]  8 MB

    // Hb = bf16(H) row-major lives in d_out scratch (dead until K5 writes out)
    bf16* Hb = (bf16*)d_out;                   // [4096][2048] bf16, 16 MB

    hipMemsetAsync(ws, 0, 24576, stream);  // de + dvr

    prep_kernel<<<dim3(E / 64, N / 64), 256, 0, stream>>>(H, ew, HT, Hb, de, dvr, N, E);
    finalize_kernel<<<dim3(16), 256, 0, stream>>>(dvr, de, ew, dv_is, wsc, N, E);

    // K3: xs_t[b*256+o][n] = (sum_d W[o][d]*x[b][n][d] + bias[o]) * dv_is[n]
    gemm_bt_conv<<<dim3(4096 / BN, 256 / BM, 8), 256, 0, stream>>>(
        W, x, 256, xs_t, 4096, bias, dv_is, 1048576LL, 1048576LL);

    // K4: t_t[c][e] = wsc[e] * sum_n xs_t[c][n] * HT[e][n]
    // grid 16x16 = 256 blocks; XCD regions 4x8
    gemm_bt_async<1, 4, 8><<<dim3(2048 / BN, 2048 / BM), 256, 0, stream>>>(
        xs_t, HT, 4096, t_t, 2048, nullptr, wsc);

    // K5: out[b][n][o] = dv_is[n] * sum_e Hb[n][e] * t_t[b*256+o][e]
    // grid 16x32 = 512 blocks; XCD regions 4x16. Hb (in d_out) fully consumed
    // by staging before any C write can land? No ordering hazard: each block
    // reads only its own A rows [rowBase,rowBase+128) of Hb, and writes only
    // out rows n in that same range -- but K5's C write targets
    // (col>>8)*1048576 + row*256 + (col&255), which as bytes overlaps OTHER
    // blocks' Hb rows. Hazard! -> stage Hb into xs_t region instead? xs_t is
    // still live (A operand of K5? no, A of K5 is Hb). xs_t dead after K4.
    // Copy Hb -> xs_t buffer region is an extra pass; instead simply point K5's
    // A at a copy placed in xs_t's 16 MB slot via a d2d async copy (graph-safe).
    hipMemcpyAsync(xs_t, Hb, 16777216, hipMemcpyDeviceToDevice, stream);
    gemm_bt_async<2, 4, 16><<<dim3(2048 / BN, 4096 / BM), 256, 0, stream>>>(
        (const bf16*)xs_t, t_t, 2048, out, 0, dv_is, nullptr);
}

// Round 6
// 241.022 us; speedup vs baseline: 1.3953x; 1.0590x over previous
//
#include <hip/hip_runtime.h>
#include <hip/hip_bf16.h>

typedef __hip_bfloat16 bf16;
typedef __bf16 bfx8 __attribute__((ext_vector_type(8)));
typedef float f32x4 __attribute__((ext_vector_type(4)));

#define BM 128

typedef __attribute__((address_space(3))) void lds_void_t;
typedef const __attribute__((address_space(1))) void gbl_void_t;

// ---------------------------------------------------------------------------
// Fused prep: HT[e][n] = bf16(H[n][e]); Hb[n][e] = bf16(H[n][e]);
// de[e] += colsum; dvr[n] += row·w.  H binary -> bf16 exact.
// grid (E/64, N/64), block 256.
__global__ void prep_kernel(const float* __restrict__ H, const float* __restrict__ w,
                            bf16* __restrict__ HT, bf16* __restrict__ Hb,
                            float* __restrict__ de, float* __restrict__ dvr, int N, int E) {
    __shared__ bf16 tile[64][65];
    __shared__ float cred[4][64];
    __shared__ float rred[4][64];
    int eb = blockIdx.x * 64, nb = blockIdx.y * 64;
    int tid = threadIdx.x;
    int c = tid & 63, g = tid >> 6;

    float cs = 0.f;
#pragma unroll
    for (int k = 0; k < 16; k++) {
        int r = g + (k << 2);
        float v = H[(size_t)(nb + r) * E + eb + c];
        bf16 bv = __float2bfloat16(v);
        tile[r][c] = bv;
        Hb[(size_t)(nb + r) * E + eb + c] = bv;   // row-major bf16 copy (coalesced in e)
        cs += v;
    }
    cred[g][c] = cs;
    __syncthreads();
    if (g == 0) {
        float s = cred[0][c] + cred[1][c] + cred[2][c] + cred[3][c];
        atomicAdd(&de[eb + c], s);
    }
    float rs = 0.f;
#pragma unroll
    for (int k = 0; k < 16; k++) {
        int cc = g + (k << 2);
        rs += __bfloat162float(tile[c][cc]) * w[eb + cc];
    }
    rred[g][c] = rs;
    __syncthreads();
    if (g == 1) {
        float s = rred[0][c] + rred[1][c] + rred[2][c] + rred[3][c];
        atomicAdd(&dvr[nb + c], s);
    }
#pragma unroll
    for (int k = 0; k < 16; k++) {
        int r = g + (k << 2);
        HT[(size_t)(eb + r) * N + nb + c] = tile[c][r];  // transposed (coalesced in n)
    }
}

__global__ void finalize_kernel(const float* __restrict__ dvr, const float* __restrict__ de,
                                const float* __restrict__ w, float* __restrict__ dv_is,
                                float* __restrict__ wsc, int N, int E) {
    int i = blockIdx.x * 256 + threadIdx.x;
    if (i < N) dv_is[i] = rsqrtf(dvr[i] + 1e-8f);
    if (i < E) wsc[i] = w[i] / (de[i] + 1e-8f);
}

// ---------------------------------------------------------------------------
// Async B^T-form GEMM, 128x64 tile, BK=64 as two stride-32 LDS sub-buffers.
// 4 waves, each 64x32 out (4x2 of 16x16x32). grid.x covers cols (BN=64).
// Swizzle (gridDim.x==32, RX=8): xcd=lin&7 owns an 8 x RY block region.
// MODE 1: Cb[row*ldc+col] = bf16(acc * cvec[col])                      (K4)
// MODE 2: Cf[(col>>8)*1048576 + row*256 + (col&255)] = acc*rvec[row]   (K5)
template <int MODE, int RY>
__global__ __launch_bounds__(256) void gemm_bt_async(
    const bf16* __restrict__ A, const bf16* __restrict__ Bt, int K,
    void* __restrict__ Cv, int ldc,
    const float* __restrict__ rvec, const float* __restrict__ cvec) {
    __shared__ __align__(16) bf16 SA[2][BM * 32];   // 16 KB
    __shared__ __align__(16) bf16 SB[2][64 * 32];   //  8 KB

    const int lin = blockIdx.y * gridDim.x + blockIdx.x;
    const int xcd = lin & 7, sidx = lin >> 3;
    const int bx = (xcd & 3) * 8 + (sidx & 7);      // col-block in [0,32)
    const int by = (xcd >> 2) * RY + (sidx >> 3);   // row-block

    const int tid     = threadIdx.x;
    const int rowBase = by * BM;
    const int colBase = bx * 64;
    const int wave = tid >> 6, lane = tid & 63;
    const int wr = (wave >> 1) * 64;
    const int wc = (wave & 1) * 32;
    const int lcol = lane & 15, quad = lane >> 4;

    // staging map: per BK=32 chunk, A = 512 chunks (2/thread), B = 256 (1/thread)
    const int sr = tid >> 2, skc = (tid & 3) << 3;
    const bf16* a0 = &A[(size_t)(rowBase + sr) * K + skc];
    const bf16* a1 = a0 + (size_t)64 * K;
    const bf16* b0 = &Bt[(size_t)(colBase + sr) * K + skc];
    bf16* d_a0[2] = {&SA[0][sr * 32 + skc], &SA[1][sr * 32 + skc]};
    bf16* d_a1[2] = {&SA[0][(sr + 64) * 32 + skc], &SA[1][(sr + 64) * 32 + skc]};
    bf16* d_b0[2] = {&SB[0][sr * 32 + skc], &SB[1][sr * 32 + skc]};

    f32x4 acc[4][2];
#pragma unroll
    for (int i = 0; i < 4; i++)
#pragma unroll
        for (int j = 0; j < 2; j++) acc[i][j] = (f32x4){0.f, 0.f, 0.f, 0.f};

    for (int k0 = 0; k0 < K; k0 += 64) {
#pragma unroll
        for (int h = 0; h < 2; h++) {
            int kk = k0 + h * 32;
            __builtin_amdgcn_global_load_lds((gbl_void_t*)(a0 + kk), (lds_void_t*)d_a0[h], 16, 0, 0);
            __builtin_amdgcn_global_load_lds((gbl_void_t*)(a1 + kk), (lds_void_t*)d_a1[h], 16, 0, 0);
            __builtin_amdgcn_global_load_lds((gbl_void_t*)(b0 + kk), (lds_void_t*)d_b0[h], 16, 0, 0);
        }
        __syncthreads();

#pragma unroll
        for (int h = 0; h < 2; h++) {
            bfx8 af[4], bfr[2];
#pragma unroll
            for (int i = 0; i < 4; i++)
                af[i] = *(const bfx8*)&SA[h][(wr + i * 16 + lcol) * 32 + quad * 8];
#pragma unroll
            for (int j = 0; j < 2; j++)
                bfr[j] = *(const bfx8*)&SB[h][(wc + j * 16 + lcol) * 32 + quad * 8];
#pragma unroll
            for (int i = 0; i < 4; i++)
#pragma unroll
                for (int j = 0; j < 2; j++)
                    acc[i][j] = __builtin_amdgcn_mfma_f32_16x16x32_bf16(af[i], bfr[j], acc[i][j], 0, 0, 0);
        }
        __syncthreads();
    }

    // C/D layout: col = lane&15, row = quad*4 + reg  [verified m89/m91]
    bf16*  Cb = (bf16*)Cv;
    float* Cf = (float*)Cv;
#pragma unroll
    for (int i = 0; i < 4; i++) {
#pragma unroll
        for (int j = 0; j < 2; j++) {
#pragma unroll
            for (int r = 0; r < 4; r++) {
                int grow = rowBase + wr + i * 16 + quad * 4 + r;
                int gcol = colBase + wc + j * 16 + lcol;
                float v = acc[i][j][r];
                if (MODE == 1) {
                    Cb[(size_t)grow * ldc + gcol] = __float2bfloat16(v * cvec[gcol]);
                } else {
                    Cf[(size_t)(gcol >> 8) * 1048576 + (size_t)grow * 256 + (gcol & 255)] =
                        v * rvec[grow];
                }
            }
        }
    }
}

// ---------------------------------------------------------------------------
// Sync-staged conv GEMM (K3): both operands f32, convert while staging.
// xs_t[bf16] = (acc + rvec[row]) * cvec[col]
__global__ __launch_bounds__(256) void gemm_bt_conv(
    const float* __restrict__ A, const float* __restrict__ B, int K,
    bf16* __restrict__ C, int ldc,
    const float* __restrict__ rvec, const float* __restrict__ cvec,
    long long bStride, long long cStride) {
    __shared__ __align__(16) bf16 As[BM * 40];
    __shared__ __align__(16) bf16 Bs[BM * 40];

    const float* Bp = B + (size_t)blockIdx.z * (size_t)bStride;
    bf16*        Cp = C + (size_t)blockIdx.z * (size_t)cStride;

    const int tid     = threadIdx.x;
    const int rowBase = blockIdx.y * BM;
    const int colBase = blockIdx.x * BM;
    const int wave = tid >> 6, lane = tid & 63;
    const int wr = (wave >> 1) * 64;
    const int wc = (wave & 1) * 64;
    const int lcol = lane & 15, quad = lane >> 4;

    f32x4 acc[4][4];
#pragma unroll
    for (int i = 0; i < 4; i++)
#pragma unroll
        for (int j = 0; j < 4; j++) acc[i][j] = (f32x4){0.f, 0.f, 0.f, 0.f};

    for (int k0 = 0; k0 < K; k0 += 32) {
#pragma unroll
        for (int c = 0; c < 2; c++) {
            int ch = tid + c * 256;
            int r = ch >> 2, kc = (ch & 3) << 3;
            size_t aoff = (size_t)(rowBase + r) * K + k0 + kc;
            size_t boff = (size_t)(colBase + r) * K + k0 + kc;
            f32x4 p0 = *(const f32x4*)&A[aoff];
            f32x4 p1 = *(const f32x4*)&A[aoff + 4];
            bfx8 va;
#pragma unroll
            for (int t = 0; t < 4; t++) { va[t] = (__bf16)p0[t]; va[4 + t] = (__bf16)p1[t]; }
            *(bfx8*)&As[r * 40 + kc] = va;
            f32x4 q0 = *(const f32x4*)&Bp[boff];
            f32x4 q1 = *(const f32x4*)&Bp[boff + 4];
            bfx8 vb;
#pragma unroll
            for (int t = 0; t < 4; t++) { vb[t] = (__bf16)q0[t]; vb[4 + t] = (__bf16)q1[t]; }
            *(bfx8*)&Bs[r * 40 + kc] = vb;
        }
        __syncthreads();

        bfx8 af[4], bfr[4];
#pragma unroll
        for (int i = 0; i < 4; i++)
            af[i] = *(const bfx8*)&As[(wr + i * 16 + lcol) * 40 + quad * 8];
#pragma unroll
        for (int j = 0; j < 4; j++)
            bfr[j] = *(const bfx8*)&Bs[(wc + j * 16 + lcol) * 40 + quad * 8];
#pragma unroll
        for (int i = 0; i < 4; i++)
#pragma unroll
            for (int j = 0; j < 4; j++)
                acc[i][j] = __builtin_amdgcn_mfma_f32_16x16x32_bf16(af[i], bfr[j], acc[i][j], 0, 0, 0);
        __syncthreads();
    }

#pragma unroll
    for (int i = 0; i < 4; i++) {
#pragma unroll
        for (int j = 0; j < 4; j++) {
#pragma unroll
            for (int r = 0; r < 4; r++) {
                int grow = rowBase + wr + i * 16 + quad * 4 + r;
                int gcol = colBase + wc + j * 16 + lcol;
                float v = (acc[i][j][r] + rvec[grow]) * cvec[gcol];
                Cp[(size_t)grow * ldc + gcol] = __float2bfloat16(v);
            }
        }
    }
}

// ---------------------------------------------------------------------------
extern "C" void kernel_launch(void* const* d_in, const int* in_sizes, int n_in,
                              void* d_out, int out_size, void* d_ws, size_t ws_size,
                              hipStream_t stream) {
    const float* x    = (const float*)d_in[0];  // [8,4096,256]
    const float* ew   = (const float*)d_in[1];  // [2048]
    const float* H    = (const float*)d_in[2];  // [4096,2048]
    const float* W    = (const float*)d_in[3];  // [256,256]
    const float* bias = (const float*)d_in[4];  // [256]
    float* out = (float*)d_out;                 // [8,4096,256] f32

    const int N = 4096, E = 2048;

    char* ws = (char*)d_ws;
    float* de    = (float*)(ws);               // 2048 f32
    float* dvr   = (float*)(ws + 8192);        // 4096 f32
    float* dv_is = (float*)(ws + 24576);       // 4096 f32
    float* wsc   = (float*)(ws + 40960);       // 2048 f32
    bf16*  HT    = (bf16*)(ws + 65536);                // [E][N] 16 MB
    bf16*  xs_t  = (bf16*)(ws + 65536 + 16777216);     // [2048][4096] 16 MB
    bf16*  t_t   = (bf16*)(ws + 65536 + 2 * 16777216); // [2048][2048]  8 MB

    // Hb = bf16(H) row-major in d_out scratch (d_out dead until K5)
    bf16* Hb = (bf16*)d_out;                   // [4096][2048] bf16, 16 MB

    hipMemsetAsync(ws, 0, 24576, stream);  // de + dvr

    prep_kernel<<<dim3(E / 64, N / 64), 256, 0, stream>>>(H, ew, HT, Hb, de, dvr, N, E);
    finalize_kernel<<<dim3(16), 256, 0, stream>>>(dvr, de, ew, dv_is, wsc, N, E);

    // K3: xs_t[b*256+o][n] = (sum_d W[o][d]*x[b][n][d] + bias[o]) * dv_is[n]
    gemm_bt_conv<<<dim3(4096 / BM, 256 / BM, 8), 256, 0, stream>>>(
        W, x, 256, xs_t, 4096, bias, dv_is, 1048576LL, 1048576LL);

    // K4: t_t[c][e] = wsc[e] * sum_n xs_t[c][n] * HT[e][n]
    // grid 32x16 = 512 blocks (2/CU); XCD regions 8x8
    gemm_bt_async<1, 8><<<dim3(32, 16), 256, 0, stream>>>(
        xs_t, HT, 4096, t_t, 2048, nullptr, wsc);

    // Hb lives in d_out which K5 overwrites -> move to xs_t slot (dead after K4)
    hipMemcpyAsync(xs_t, Hb, 16777216, hipMemcpyDeviceToDevice, stream);

    // K5: out[b][n][o] = dv_is[n] * sum_e Hb[n][e] * t_t[b*256+o][e]
    // grid 32x32 = 1024 blocks (4/CU); XCD regions 8x16
    gemm_bt_async<2, 16><<<dim3(32, 32), 256, 0, stream>>>(
        (const bf16*)xs_t, t_t, 2048, out, 0, dv_is, nullptr);
}

// Round 7
// 234.287 us; speedup vs baseline: 1.4354x; 1.0287x over previous
//
#include <hip/hip_runtime.h>
#include <hip/hip_bf16.h>

typedef __hip_bfloat16 bf16;
typedef __bf16 bfx8 __attribute__((ext_vector_type(8)));
typedef float f32x4 __attribute__((ext_vector_type(4)));

#define BM 128

typedef __attribute__((address_space(3))) void lds_void_t;
typedef const __attribute__((address_space(1))) void gbl_void_t;

// ---------------------------------------------------------------------------
// Fused prep: HT[e][n] = bf16(H[n][e]); Hb[n][e] = bf16(H[n][e]);
// de[e] += colsum; dvr[n] += row·w.  H binary -> bf16 exact.
// grid (E/64, N/64), block 256.
__global__ void prep_kernel(const float* __restrict__ H, const float* __restrict__ w,
                            bf16* __restrict__ HT, bf16* __restrict__ Hb,
                            float* __restrict__ de, float* __restrict__ dvr, int N, int E) {
    __shared__ bf16 tile[64][65];
    __shared__ float cred[4][64];
    __shared__ float rred[4][64];
    int eb = blockIdx.x * 64, nb = blockIdx.y * 64;
    int tid = threadIdx.x;
    int c = tid & 63, g = tid >> 6;

    float cs = 0.f;
#pragma unroll
    for (int k = 0; k < 16; k++) {
        int r = g + (k << 2);
        float v = H[(size_t)(nb + r) * E + eb + c];
        bf16 bv = __float2bfloat16(v);
        tile[r][c] = bv;
        Hb[(size_t)(nb + r) * E + eb + c] = bv;   // row-major bf16 copy (coalesced in e)
        cs += v;
    }
    cred[g][c] = cs;
    __syncthreads();
    if (g == 0) {
        float s = cred[0][c] + cred[1][c] + cred[2][c] + cred[3][c];
        atomicAdd(&de[eb + c], s);
    }
    float rs = 0.f;
#pragma unroll
    for (int k = 0; k < 16; k++) {
        int cc = g + (k << 2);
        rs += __bfloat162float(tile[c][cc]) * w[eb + cc];
    }
    rred[g][c] = rs;
    __syncthreads();
    if (g == 1) {
        float s = rred[0][c] + rred[1][c] + rred[2][c] + rred[3][c];
        atomicAdd(&dvr[nb + c], s);
    }
#pragma unroll
    for (int k = 0; k < 16; k++) {
        int r = g + (k << 2);
        HT[(size_t)(eb + r) * N + nb + c] = tile[c][r];  // transposed (coalesced in n)
    }
}

__global__ void finalize_kernel(const float* __restrict__ dvr, const float* __restrict__ de,
                                const float* __restrict__ w, float* __restrict__ dv_is,
                                float* __restrict__ wsc, int N, int E) {
    int i = blockIdx.x * 256 + threadIdx.x;
    if (i < N) dv_is[i] = rsqrtf(dvr[i] + 1e-8f);
    if (i < E) wsc[i] = w[i] / (de[i] + 1e-8f);
}

// t_t[c][e] = bf16((s0+s1) * wsc[e]); 8 elems/thread, E=2048 divides 8 ✓
__global__ void combine_kernel(const bf16* __restrict__ s0, const bf16* __restrict__ s1,
                               const float* __restrict__ wsc, bf16* __restrict__ tt) {
    size_t i = ((size_t)blockIdx.x * 256 + threadIdx.x) * 8;
    size_t e = i & 2047;
    bfx8 a = *(const bfx8*)&s0[i];
    bfx8 b = *(const bfx8*)&s1[i];
    bfx8 v;
#pragma unroll
    for (int t = 0; t < 8; t++)
        v[t] = (__bf16)(((float)a[t] + (float)b[t]) * wsc[e + t]);
    *(bfx8*)&tt[i] = v;
}

// ---------------------------------------------------------------------------
// Async B^T-form GEMM, 128x64 tile, BK=64 as two stride-32 LDS sub-buffers.
// 4 waves, each 64x32 out (4x2 of 16x16x32). grid.x covers cols (BN=64).
// Swizzle (gridDim.x==32): xcd = lin&7 owns an 8 x RY block region per z-plane.
// Kst = operand row stride; kLen = K-range per z-slice (kBase = z*kLen, MODE 3).
// MODE 2: Cf[(col>>8)*1048576 + row*256 + (col&255)] = acc*rvec[row]   (K5)
// MODE 3: Cb[z*4194304 + row*ldc + col] = bf16(acc)    (K4 split-K partials)
template <int MODE, int RY>
__global__ __launch_bounds__(256) void gemm_bt_async(
    const bf16* __restrict__ A, const bf16* __restrict__ Bt, int Kst, int kLen,
    void* __restrict__ Cv, int ldc,
    const float* __restrict__ rvec, const float* __restrict__ cvec) {
    __shared__ __align__(16) bf16 SA[2][BM * 32];   // 16 KB
    __shared__ __align__(16) bf16 SB[2][64 * 32];   //  8 KB

    const int lin = blockIdx.y * gridDim.x + blockIdx.x;
    const int xcd = lin & 7, sidx = lin >> 3;
    const int bx = (xcd & 3) * 8 + (sidx & 7);      // col-block in [0,32)
    const int by = (xcd >> 2) * RY + (sidx >> 3);   // row-block

    const int kBase = (MODE == 3) ? blockIdx.z * kLen : 0;

    const int tid     = threadIdx.x;
    const int rowBase = by * BM;
    const int colBase = bx * 64;
    const int wave = tid >> 6, lane = tid & 63;
    const int wr = (wave >> 1) * 64;
    const int wc = (wave & 1) * 32;
    const int lcol = lane & 15, quad = lane >> 4;

    // staging map: per BK=32 chunk, A = 512 chunks (2/thread), B = 256 (1/thread)
    const int sr = tid >> 2, skc = (tid & 3) << 3;
    const bf16* a0 = &A[(size_t)(rowBase + sr) * Kst + kBase + skc];
    const bf16* a1 = a0 + (size_t)64 * Kst;
    const bf16* b0 = &Bt[(size_t)(colBase + sr) * Kst + kBase + skc];
    bf16* d_a0[2] = {&SA[0][sr * 32 + skc], &SA[1][sr * 32 + skc]};
    bf16* d_a1[2] = {&SA[0][(sr + 64) * 32 + skc], &SA[1][(sr + 64) * 32 + skc]};
    bf16* d_b0[2] = {&SB[0][sr * 32 + skc], &SB[1][sr * 32 + skc]};

    f32x4 acc[4][2];
#pragma unroll
    for (int i = 0; i < 4; i++)
#pragma unroll
        for (int j = 0; j < 2; j++) acc[i][j] = (f32x4){0.f, 0.f, 0.f, 0.f};

    for (int k0 = 0; k0 < kLen; k0 += 64) {
#pragma unroll
        for (int h = 0; h < 2; h++) {
            int kk = k0 + h * 32;
            __builtin_amdgcn_global_load_lds((gbl_void_t*)(a0 + kk), (lds_void_t*)d_a0[h], 16, 0, 0);
            __builtin_amdgcn_global_load_lds((gbl_void_t*)(a1 + kk), (lds_void_t*)d_a1[h], 16, 0, 0);
            __builtin_amdgcn_global_load_lds((gbl_void_t*)(b0 + kk), (lds_void_t*)d_b0[h], 16, 0, 0);
        }
        __syncthreads();

#pragma unroll
        for (int h = 0; h < 2; h++) {
            bfx8 af[4], bfr[2];
#pragma unroll
            for (int i = 0; i < 4; i++)
                af[i] = *(const bfx8*)&SA[h][(wr + i * 16 + lcol) * 32 + quad * 8];
#pragma unroll
            for (int j = 0; j < 2; j++)
                bfr[j] = *(const bfx8*)&SB[h][(wc + j * 16 + lcol) * 32 + quad * 8];
#pragma unroll
            for (int i = 0; i < 4; i++)
#pragma unroll
                for (int j = 0; j < 2; j++)
                    acc[i][j] = __builtin_amdgcn_mfma_f32_16x16x32_bf16(af[i], bfr[j], acc[i][j], 0, 0, 0);
        }
        __syncthreads();
    }

    // C/D layout: col = lane&15, row = quad*4 + reg  [verified m89/m91]
    bf16*  Cb = (bf16*)Cv;
    float* Cf = (float*)Cv;
    const size_t sliceOff = (MODE == 3) ? (size_t)blockIdx.z * 4194304 : 0;
#pragma unroll
    for (int i = 0; i < 4; i++) {
#pragma unroll
        for (int j = 0; j < 2; j++) {
#pragma unroll
            for (int r = 0; r < 4; r++) {
                int grow = rowBase + wr + i * 16 + quad * 4 + r;
                int gcol = colBase + wc + j * 16 + lcol;
                float v = acc[i][j][r];
                if (MODE == 3) {
                    Cb[sliceOff + (size_t)grow * ldc + gcol] = __float2bfloat16(v);
                } else {
                    Cf[(size_t)(gcol >> 8) * 1048576 + (size_t)grow * 256 + (gcol & 255)] =
                        v * rvec[grow];
                }
            }
        }
    }
}

// ---------------------------------------------------------------------------
// Sync-staged conv GEMM (K3): both operands f32, convert while staging.
// xs_t[bf16] = (acc + rvec[row]) * cvec[col]
__global__ __launch_bounds__(256) void gemm_bt_conv(
    const float* __restrict__ A, const float* __restrict__ B, int K,
    bf16* __restrict__ C, int ldc,
    const float* __restrict__ rvec, const float* __restrict__ cvec,
    long long bStride, long long cStride) {
    __shared__ __align__(16) bf16 As[BM * 40];
    __shared__ __align__(16) bf16 Bs[BM * 40];

    const float* Bp = B + (size_t)blockIdx.z * (size_t)bStride;
    bf16*        Cp = C + (size_t)blockIdx.z * (size_t)cStride;

    const int tid     = threadIdx.x;
    const int rowBase = blockIdx.y * BM;
    const int colBase = blockIdx.x * BM;
    const int wave = tid >> 6, lane = tid & 63;
    const int wr = (wave >> 1) * 64;
    const int wc = (wave & 1) * 64;
    const int lcol = lane & 15, quad = lane >> 4;

    f32x4 acc[4][4];
#pragma unroll
    for (int i = 0; i < 4; i++)
#pragma unroll
        for (int j = 0; j < 4; j++) acc[i][j] = (f32x4){0.f, 0.f, 0.f, 0.f};

    for (int k0 = 0; k0 < K; k0 += 32) {
#pragma unroll
        for (int c = 0; c < 2; c++) {
            int ch = tid + c * 256;
            int r = ch >> 2, kc = (ch & 3) << 3;
            size_t aoff = (size_t)(rowBase + r) * K + k0 + kc;
            size_t boff = (size_t)(colBase + r) * K + k0 + kc;
            f32x4 p0 = *(const f32x4*)&A[aoff];
            f32x4 p1 = *(const f32x4*)&A[aoff + 4];
            bfx8 va;
#pragma unroll
            for (int t = 0; t < 4; t++) { va[t] = (__bf16)p0[t]; va[4 + t] = (__bf16)p1[t]; }
            *(bfx8*)&As[r * 40 + kc] = va;
            f32x4 q0 = *(const f32x4*)&Bp[boff];
            f32x4 q1 = *(const f32x4*)&Bp[boff + 4];
            bfx8 vb;
#pragma unroll
            for (int t = 0; t < 4; t++) { vb[t] = (__bf16)q0[t]; vb[4 + t] = (__bf16)q1[t]; }
            *(bfx8*)&Bs[r * 40 + kc] = vb;
        }
        __syncthreads();

        bfx8 af[4], bfr[4];
#pragma unroll
        for (int i = 0; i < 4; i++)
            af[i] = *(const bfx8*)&As[(wr + i * 16 + lcol) * 40 + quad * 8];
#pragma unroll
        for (int j = 0; j < 4; j++)
            bfr[j] = *(const bfx8*)&Bs[(wc + j * 16 + lcol) * 40 + quad * 8];
#pragma unroll
        for (int i = 0; i < 4; i++)
#pragma unroll
            for (int j = 0; j < 4; j++)
                acc[i][j] = __builtin_amdgcn_mfma_f32_16x16x32_bf16(af[i], bfr[j], acc[i][j], 0, 0, 0);
        __syncthreads();
    }

#pragma unroll
    for (int i = 0; i < 4; i++) {
#pragma unroll
        for (int j = 0; j < 4; j++) {
#pragma unroll
            for (int r = 0; r < 4; r++) {
                int grow = rowBase + wr + i * 16 + quad * 4 + r;
                int gcol = colBase + wc + j * 16 + lcol;
                float v = (acc[i][j][r] + rvec[grow]) * cvec[gcol];
                Cp[(size_t)grow * ldc + gcol] = __float2bfloat16(v);
            }
        }
    }
}

// ---------------------------------------------------------------------------
extern "C" void kernel_launch(void* const* d_in, const int* in_sizes, int n_in,
                              void* d_out, int out_size, void* d_ws, size_t ws_size,
                              hipStream_t stream) {
    const float* x    = (const float*)d_in[0];  // [8,4096,256]
    const float* ew   = (const float*)d_in[1];  // [2048]
    const float* H    = (const float*)d_in[2];  // [4096,2048]
    const float* W    = (const float*)d_in[3];  // [256,256]
    const float* bias = (const float*)d_in[4];  // [256]
    float* out = (float*)d_out;                 // [8,4096,256] f32, 33.55 MB

    const int N = 4096, E = 2048;

    char* ws = (char*)d_ws;
    float* de    = (float*)(ws);               // 2048 f32
    float* dvr   = (float*)(ws + 8192);        // 4096 f32
    float* dv_is = (float*)(ws + 24576);       // 4096 f32
    float* wsc   = (float*)(ws + 40960);       // 2048 f32
    bf16*  HT    = (bf16*)(ws + 65536);                // [E][N] 16 MB
    bf16*  xs_t  = (bf16*)(ws + 65536 + 16777216);     // [2048][4096] 16 MB
    bf16*  t_t   = (bf16*)(ws + 65536 + 2 * 16777216); // [2048][2048]  8 MB

    // d_out scratch map (dead until K5's final write):
    // [0:16MB)   Hb = bf16(H) row-major
    // [16:24MB)  K4 split-K slice 0 (bf16 [2048][2048])
    // [24:32MB)  K4 split-K slice 1
    bf16* Hb     = (bf16*)d_out;
    bf16* slices = (bf16*)((char*)d_out + 16777216);

    hipMemsetAsync(ws, 0, 24576, stream);  // de + dvr

    prep_kernel<<<dim3(E / 64, N / 64), 256, 0, stream>>>(H, ew, HT, Hb, de, dvr, N, E);
    finalize_kernel<<<dim3(16), 256, 0, stream>>>(dvr, de, ew, dv_is, wsc, N, E);

    // K3: xs_t[b*256+o][n] = (sum_d W[o][d]*x[b][n][d] + bias[o]) * dv_is[n]
    gemm_bt_conv<<<dim3(4096 / BM, 256 / BM, 8), 256, 0, stream>>>(
        W, x, 256, xs_t, 4096, bias, dv_is, 1048576LL, 1048576LL);

    // K4 split-K=2: slice[z][c][e] = sum_{n in z-half} xs_t[c][n] * HT[e][n]
    // grid 32x16x2 = 1024 blocks (4/CU); per-plane XCD regions 8x8
    gemm_bt_async<3, 8><<<dim3(32, 16, 2), 256, 0, stream>>>(
        xs_t, HT, 4096, 2048, slices, 2048, nullptr, nullptr);

    // t_t = bf16((s0+s1) * wsc[e])
    combine_kernel<<<dim3(2048), 256, 0, stream>>>(
        slices, slices + 4194304, wsc, t_t);

    // Hb lives in d_out which K5 overwrites -> move to xs_t slot (dead after K4)
    hipMemcpyAsync(xs_t, Hb, 16777216, hipMemcpyDeviceToDevice, stream);

    // K5: out[b][n][o] = dv_is[n] * sum_e Hb[n][e] * t_t[b*256+o][e]
    // grid 32x32 = 1024 blocks (4/CU); XCD regions 8x16
    gemm_bt_async<2, 16><<<dim3(32, 32), 256, 0, stream>>>(
        (const bf16*)xs_t, t_t, 2048, 2048, out, 0, dv_is, nullptr);
}